// Round 1
// baseline (352.089 us; speedup 1.0000x reference)
//
#include <hip/hip_runtime.h>

#define BIG 3.0e38f

// ---------------------------------------------------------------------------
// Branchy top-3 insert (strict < keeps lowest index on ties, matching top_k).
// ---------------------------------------------------------------------------
__device__ __forceinline__ void insert3(float d, int s,
                                        float& d0, float& d1, float& d2,
                                        int& i0, int& i1, int& i2) {
    if (d < d2) {
        if (d < d1) {
            if (d < d0) {
                d2 = d1; i2 = i1;
                d1 = d0; i1 = i0;
                d0 = d;  i0 = s;
            } else {
                d2 = d1; i2 = i1;
                d1 = d;  i1 = s;
            }
        } else {
            d2 = d; i2 = s;
        }
    }
}

// ---------------------------------------------------------------------------
// Single-pass KNN for one 64-query tile. 256 threads = 64 queries x 4 splits.
// All S candidates staged once in LDS (float4: x,y,z,|p|^2); each thread scans
// its split's SPC candidates; split top-3 lists merged in LDS (split order ->
// tie order matches a full ascending scan). Writes idx/w directly: no pd/pi
// round-trip, no merge kernel.
// ---------------------------------------------------------------------------
template <int S, int SPC>
__device__ void knn_tile(const float* __restrict__ xyzF, const float* __restrict__ xyzC,
                         int N, int b, int nb,
                         int* __restrict__ idx, float* __restrict__ w,
                         void* smem) {
    float4* sc  = (float4*)smem;                       // S * 16 B
    float*  smd = (float*)((char*)smem + S * 16);      // [256][3] floats
    int*    smi = (int*)((char*)smem + S * 16 + 3072); // [256][3] ints
    const int tid = threadIdx.x;

    for (int i = tid; i < S; i += 256) {
        const float x = xyzC[(b * S + i) * 3 + 0];
        const float y = xyzC[(b * S + i) * 3 + 1];
        const float z = xyzC[(b * S + i) * 3 + 2];
        sc[i] = make_float4(x, y, z, x * x + y * y + z * z);
    }
    __syncthreads();

    const int q  = tid & 63;
    const int sp = tid >> 6;          // wave index == split index (uniform per wave)
    const int n  = nb + q;
    const float ax = xyzF[(b * N + n) * 3 + 0];
    const float ay = xyzF[(b * N + n) * 3 + 1];
    const float az = xyzF[(b * N + n) * 3 + 2];
    const float an = ax * ax + ay * ay + az * az;

    float d0 = BIG, d1 = BIG, d2 = BIG;
    int i0 = 0, i1 = 0, i2 = 0;
    const int s0 = sp * SPC;
#pragma unroll 4
    for (int s = s0; s < s0 + SPC; ++s) {
        const float4 p = sc[s];       // uniform within wave -> LDS broadcast
        const float t = ax * p.x + ay * p.y + az * p.z;
        const float d = an + p.w - 2.0f * t;   // matches ref formula exactly
        insert3(d, s, d0, d1, d2, i0, i1, i2);
    }

    smd[tid * 3 + 0] = d0; smi[tid * 3 + 0] = i0;
    smd[tid * 3 + 1] = d1; smi[tid * 3 + 1] = i1;
    smd[tid * 3 + 2] = d2; smi[tid * 3 + 2] = i2;
    __syncthreads();

    if (tid < 64) {                    // one thread per query merges 4 splits
        float e0 = BIG, e1 = BIG, e2 = BIG;
        int j0 = 0, j1 = 0, j2 = 0;
#pragma unroll
        for (int ch = 0; ch < 4; ++ch) {
#pragma unroll
            for (int k = 0; k < 3; ++k) {
                insert3(smd[(ch * 64 + tid) * 3 + k], smi[(ch * 64 + tid) * 3 + k],
                        e0, e1, e2, j0, j1, j2);
            }
        }
        const float r0 = 1.0f / (e0 + 1e-8f);
        const float r1 = 1.0f / (e1 + 1e-8f);
        const float r2 = 1.0f / (e2 + 1e-8f);
        const float rs = r0 + r1 + r2;
        const int nn = nb + tid;
        idx[(b * 3 + 0) * N + nn] = j0;
        idx[(b * 3 + 1) * N + nn] = j1;
        idx[(b * 3 + 2) * N + nn] = j2;
        w[(b * 3 + 0) * N + nn] = r0 / rs;
        w[(b * 3 + 1) * N + nn] = r1 / rs;
        w[(b * 3 + 2) * N + nn] = r2 / rs;
    }
}

// ---------------------------------------------------------------------------
// 64x64 tile transpose [B,C,N] -> point-major out[b][n][co+c] (row stride OS).
// ---------------------------------------------------------------------------
__device__ void transpose_tile(const float* __restrict__ in, float* __restrict__ out,
                               int C, int N, int OS, int co,
                               int b, int nb, int cb, void* smem) {
    float (*s)[65] = (float (*)[65])smem;
    const int lo = threadIdx.x & 63;
    const int r  = threadIdx.x >> 6;
#pragma unroll
    for (int i = 0; i < 16; ++i) {
        const int cl = r + 4 * i;
        s[cl][lo] = in[((size_t)b * C + cb + cl) * N + nb + lo];
    }
    __syncthreads();
#pragma unroll
    for (int i = 0; i < 16; ++i) {
        const int pl = r + 4 * i;
        out[((size_t)b * N + nb + pl) * OS + co + cb + lo] = s[lo][pl];
    }
}

// ---------------------------------------------------------------------------
// K1: all mutually-independent work fused; block-range dispatch. knn2 blocks
// first (longest pole), memory-bound blocks overlap underneath.
//   [   0, 512)  knn stage-2: xyz0 vs xyz1 -> idx2/w2   (512 blocks)
//   [ 512, 640)  knn stage-1: xyz1 vs xyz2 -> idx1/w1   (128 blocks)
//   [ 640, 896)  t_x2: x2 -> x2P (point-major 512x512)  (256 blocks)
//   [ 896,1408)  t_x1: x1 -> featP cols 0..255          (512 blocks)
//   [1408,1664)  copy x0 -> out channels 0..127         (256 blocks)
// ---------------------------------------------------------------------------
__global__ __launch_bounds__(256) void fused_stage(const float* __restrict__ xyz0,
                                                   const float* __restrict__ xyz1,
                                                   const float* __restrict__ xyz2,
                                                   const float* __restrict__ x0,
                                                   const float* __restrict__ x1,
                                                   const float* __restrict__ x2,
                                                   float* __restrict__ featP,
                                                   float* __restrict__ x2P,
                                                   int* __restrict__ idx1,
                                                   float* __restrict__ w1,
                                                   int* __restrict__ idx2,
                                                   float* __restrict__ w2,
                                                   float* __restrict__ out) {
    __shared__ float4 smem4[2432];   // 38,912 B union: knn2 (38.9K) / transpose (16.6K)
    const int id = blockIdx.x;
    if (id < 512) {
        const int b  = id >> 7;
        const int nb = (id & 127) * 64;
        knn_tile<2048, 512>(xyz0, xyz1, 8192, b, nb, idx2, w2, smem4);
    } else if (id < 640) {
        const int r  = id - 512;
        const int b  = r >> 5;
        const int nb = (r & 31) * 64;
        knn_tile<512, 128>(xyz1, xyz2, 2048, b, nb, idx1, w1, smem4);
    } else if (id < 896) {
        const int r  = id - 640;
        const int b  = r >> 6;
        const int nb = (r & 7) * 64;
        const int cb = ((r >> 3) & 7) * 64;
        transpose_tile(x2, x2P, 512, 512, 512, 0, b, nb, cb, smem4);
    } else if (id < 1408) {
        const int r  = id - 896;
        const int b  = r >> 7;
        const int nb = (r & 31) * 64;
        const int cb = ((r >> 5) & 3) * 64;
        transpose_tile(x1, featP, 256, 2048, 768, 0, b, nb, cb, smem4);
    } else {
        const int r  = id - 1408;          // 0..255
        const int b  = r >> 6;
        const int lb = r & 63;
        const float4* src = (const float4*)x0;
        float4* dst = (float4*)out;
#pragma unroll
        for (int t = 0; t < 16; ++t) {
            const int i = lb * 4096 + t * 256 + threadIdx.x;   // 0..262143
            dst[(size_t)b * (896 * 2048) + i] = src[(size_t)b * (128 * 2048) + i];
        }
    }
}

// ---------------------------------------------------------------------------
// Stage-1 interp, point-major (unchanged): featP[b][n][256+c] = sum_k w*x2P[j][c]
// ---------------------------------------------------------------------------
__global__ __launch_bounds__(256) void interp1(const float* __restrict__ x2P,
                                               const int* __restrict__ idx,
                                               const float* __restrict__ w,
                                               float* __restrict__ featP) {
    __shared__ int   sj[3][64];
    __shared__ float sw[3][64];
    const int b = blockIdx.z;
    const int nb = blockIdx.x * 64;
    const int cb = blockIdx.y * 64;
    const int tid = threadIdx.x;

    if (tid < 64) {
#pragma unroll
        for (int k = 0; k < 3; ++k) {
            sj[k][tid] = idx[(b * 3 + k) * 2048 + nb + tid];
            sw[k][tid] = w[(b * 3 + k) * 2048 + nb + tid];
        }
    }
    __syncthreads();

    const int c = tid & 63, r = tid >> 6;
#pragma unroll
    for (int i = 0; i < 16; ++i) {
        const int p = r + 4 * i;
        const float v = sw[0][p] * x2P[((size_t)b * 512 + sj[0][p]) * 512 + cb + c]
                      + sw[1][p] * x2P[((size_t)b * 512 + sj[1][p]) * 512 + cb + c]
                      + sw[2][p] * x2P[((size_t)b * 512 + sj[2][p]) * 512 + cb + c];
        featP[((size_t)b * 2048 + nb + p) * 768 + 256 + cb + c] = v;
    }
}

// ---------------------------------------------------------------------------
// Final interp (unchanged): out[b][128+c][n] = sum_k w_k * featP[b][j_k][c].
// XCD swizzle: all 12 c-tiles of an n-tile on the same XCD.
// ---------------------------------------------------------------------------
__global__ __launch_bounds__(256) void final_interp(const float* __restrict__ featP,
                                                    const int* __restrict__ idx,
                                                    const float* __restrict__ w,
                                                    float* __restrict__ out) {
    __shared__ float tile[64][65];
    __shared__ int   sj[3][64];
    __shared__ float sw[3][64];
    const int b = blockIdx.y;
    const int id = blockIdx.x;
    const int ntile = (id & 7) * 16 + ((id >> 3) & 15);
    const int ctile = id >> 7;
    const int nb = ntile * 64;
    const int cb = ctile * 64;
    const int tid = threadIdx.x;

    if (tid < 64) {
#pragma unroll
        for (int k = 0; k < 3; ++k) {
            sj[k][tid] = idx[(b * 3 + k) * 8192 + nb + tid];
            sw[k][tid] = w[(b * 3 + k) * 8192 + nb + tid];
        }
    }
    __syncthreads();

    {
        const int c = tid & 63, r = tid >> 6;
#pragma unroll
        for (int i = 0; i < 16; ++i) {
            const int p = r + 4 * i;
            const float v = sw[0][p] * featP[((size_t)b * 2048 + sj[0][p]) * 768 + cb + c]
                          + sw[1][p] * featP[((size_t)b * 2048 + sj[1][p]) * 768 + cb + c]
                          + sw[2][p] * featP[((size_t)b * 2048 + sj[2][p]) * 768 + cb + c];
            tile[p][c] = v;
        }
    }
    __syncthreads();
    {
        const int p = tid & 63, r = tid >> 6;
#pragma unroll
        for (int i = 0; i < 16; ++i) {
            const int cl = r + 4 * i;
            out[((size_t)b * 896 + 128 + cb + cl) * 8192 + nb + p] = tile[p][cl];
        }
    }
}

extern "C" void kernel_launch(void* const* d_in, const int* in_sizes, int n_in,
                              void* d_out, int out_size, void* d_ws, size_t ws_size,
                              hipStream_t stream) {
    const float* xyz0 = (const float*)d_in[0];  // [4,8192,3]
    const float* xyz1 = (const float*)d_in[1];  // [4,2048,3]
    const float* xyz2 = (const float*)d_in[2];  // [4,512,3]
    const float* x0   = (const float*)d_in[3];  // [4,128,8192]
    const float* x1   = (const float*)d_in[4];  // [4,256,2048]
    const float* x2   = (const float*)d_in[5];  // [4,512,512]
    float* out = (float*)d_out;                 // [4,896,8192]

    // Workspace layout (bytes), no aliasing (total 30,343,168):
    //   featP : float[4*2048*768]  @ 0          (25,165,824)
    //   idx1  : int  [4*3*2048]    @ 25,165,824 (98,304)
    //   w1    : float[4*3*2048]    @ 25,264,128 (98,304)
    //   idx2  : int  [4*3*8192]    @ 25,362,432 (393,216)
    //   w2    : float[4*3*8192]    @ 25,755,648 (393,216)
    //   x2P   : float[4*512*512]   @ 26,148,864 (4,194,304)
    char* ws = (char*)d_ws;
    float* featP = (float*)(ws + 0);
    int*   idx1  = (int*)(ws + 25165824);
    float* w1    = (float*)(ws + 25264128);
    int*   idx2  = (int*)(ws + 25362432);
    float* w2    = (float*)(ws + 25755648);
    float* x2P   = (float*)(ws + 26148864);

    // K1: both KNNs (direct idx/w output) + both transposes + x0 copy, fused.
    fused_stage<<<dim3(1664), 256, 0, stream>>>(xyz0, xyz1, xyz2, x0, x1, x2,
                                                featP, x2P, idx1, w1, idx2, w2, out);
    // K2: stage-1 interpolation into featP cols 256..767.
    interp1<<<dim3(32, 8, 4), 256, 0, stream>>>(x2P, idx1, w1, featP);
    // K3: final interpolation into out channels 128..895.
    final_interp<<<dim3(1536, 4), 256, 0, stream>>>(featP, idx2, w2, out);
}

// Round 2
// 218.066 us; speedup vs baseline: 1.6146x; 1.6146x over previous
//
#include <hip/hip_runtime.h>

#define BIG 3.0e38f

// ---------------------------------------------------------------------------
// Branchless top-3 insert (strict < keeps lowest index on ties, matching
// top_k). Straight-line: 3 v_cmp + 10 v_cndmask, no exec-mask churn, so the
// surrounding scan loop stays a single basic block and the compiler can
// unroll + software-pipeline the LDS reads.
// ---------------------------------------------------------------------------
__device__ __forceinline__ void insert3(float d, int s,
                                        float& d0, float& d1, float& d2,
                                        int& i0, int& i1, int& i2) {
    const bool b0 = d < d0;
    const bool b1 = d < d1;
    const bool b2 = d < d2;
    d2 = b1 ? d1 : (b2 ? d : d2);   // reads old d1/i1
    i2 = b1 ? i1 : (b2 ? s : i2);
    d1 = b0 ? d0 : (b1 ? d : d1);   // reads old d0/i0
    i1 = b0 ? i0 : (b1 ? s : i1);
    d0 = b0 ? d : d0;
    i0 = b0 ? s : i0;
}

// ---------------------------------------------------------------------------
// Single-pass KNN tile: 256 threads = 32 queries x 8 candidate-splits.
// All S candidates staged once in LDS (float4: x,y,z,|p|^2). Each thread
// scans S/8 candidates (short serial chain); 8 split top-3 lists merged in
// LDS in ascending split order (tie order == full ascending scan). Writes
// idx/w directly -- no pd/pi round-trip, no merge kernel.
// knn2: S=2048 -> 1024 blocks, 256-iter chains (round-0 occupancy geometry).
// ---------------------------------------------------------------------------
template <int S>
__device__ void knn_tile(const float* __restrict__ xyzF, const float* __restrict__ xyzC,
                         int N, int b, int nb,
                         int* __restrict__ idx, float* __restrict__ w,
                         void* smem) {
    constexpr int SPC = S / 8;
    float4* sc  = (float4*)smem;                       // S * 16 B
    float*  smd = (float*)((char*)smem + S * 16);      // [256][3] floats
    int*    smi = (int*)((char*)smem + S * 16 + 3072); // [256][3] ints
    const int tid = threadIdx.x;

    for (int i = tid; i < S; i += 256) {
        const float x = xyzC[(b * S + i) * 3 + 0];
        const float y = xyzC[(b * S + i) * 3 + 1];
        const float z = xyzC[(b * S + i) * 3 + 2];
        sc[i] = make_float4(x, y, z, x * x + y * y + z * z);
    }
    __syncthreads();

    const int q  = tid & 31;          // query within tile
    const int sp = tid >> 5;          // candidate split 0..7
    const int n  = nb + q;
    const float ax = xyzF[(b * N + n) * 3 + 0];
    const float ay = xyzF[(b * N + n) * 3 + 1];
    const float az = xyzF[(b * N + n) * 3 + 2];
    const float an = ax * ax + ay * ay + az * az;

    float d0 = BIG, d1 = BIG, d2 = BIG;
    int i0 = 0, i1 = 0, i2 = 0;
    const int s0 = sp * SPC;
#pragma unroll 8
    for (int s = s0; s < s0 + SPC; ++s) {
        const float4 p = sc[s];       // 2 distinct addrs per wave -> ~free
        const float t = ax * p.x + ay * p.y + az * p.z;
        const float d = an + p.w - 2.0f * t;   // matches ref formula exactly
        insert3(d, s, d0, d1, d2, i0, i1, i2);
    }

    smd[tid * 3 + 0] = d0; smi[tid * 3 + 0] = i0;   // stride 3 -> <=2-way, free
    smd[tid * 3 + 1] = d1; smi[tid * 3 + 1] = i1;
    smd[tid * 3 + 2] = d2; smi[tid * 3 + 2] = i2;
    __syncthreads();

    if (tid < 32) {                   // one thread per query merges 8 splits
        float e0 = BIG, e1 = BIG, e2 = BIG;
        int j0 = 0, j1 = 0, j2 = 0;
#pragma unroll
        for (int ch = 0; ch < 8; ++ch) {
#pragma unroll
            for (int k = 0; k < 3; ++k) {
                insert3(smd[(ch * 32 + tid) * 3 + k], smi[(ch * 32 + tid) * 3 + k],
                        e0, e1, e2, j0, j1, j2);
            }
        }
        const float r0 = 1.0f / (e0 + 1e-8f);
        const float r1 = 1.0f / (e1 + 1e-8f);
        const float r2 = 1.0f / (e2 + 1e-8f);
        const float rs = r0 + r1 + r2;
        const int nn = nb + tid;
        idx[(b * 3 + 0) * N + nn] = j0;
        idx[(b * 3 + 1) * N + nn] = j1;
        idx[(b * 3 + 2) * N + nn] = j2;
        w[(b * 3 + 0) * N + nn] = r0 / rs;
        w[(b * 3 + 1) * N + nn] = r1 / rs;
        w[(b * 3 + 2) * N + nn] = r2 / rs;
    }
}

// ---------------------------------------------------------------------------
// 64x64 tile transpose [B,C,N] -> point-major out[b][n][co+c] (row stride OS).
// ---------------------------------------------------------------------------
__device__ void transpose_tile(const float* __restrict__ in, float* __restrict__ out,
                               int C, int N, int OS, int co,
                               int b, int nb, int cb, void* smem) {
    float (*s)[65] = (float (*)[65])smem;
    const int lo = threadIdx.x & 63;
    const int r  = threadIdx.x >> 6;
#pragma unroll
    for (int i = 0; i < 16; ++i) {
        const int cl = r + 4 * i;
        s[cl][lo] = in[((size_t)b * C + cb + cl) * N + nb + lo];
    }
    __syncthreads();
#pragma unroll
    for (int i = 0; i < 16; ++i) {
        const int pl = r + 4 * i;
        out[((size_t)b * N + nb + pl) * OS + co + cb + lo] = s[lo][pl];
    }
}

// ---------------------------------------------------------------------------
// Stage-1 interp tile, point-major: featP[b][n][256+c] = sum_k w*x2P[j_k][c].
// ---------------------------------------------------------------------------
__device__ void interp1_tile(const float* __restrict__ x2P,
                             const int* __restrict__ idx, const float* __restrict__ w,
                             float* __restrict__ featP,
                             int b, int nb, int cb, void* smem) {
    int*   sj = (int*)smem;                    // [3][64]
    float* sw = (float*)((char*)smem + 768);   // [3][64]
    const int tid = threadIdx.x;

    if (tid < 64) {
#pragma unroll
        for (int k = 0; k < 3; ++k) {
            sj[k * 64 + tid] = idx[(b * 3 + k) * 2048 + nb + tid];
            sw[k * 64 + tid] = w[(b * 3 + k) * 2048 + nb + tid];
        }
    }
    __syncthreads();

    const int c = tid & 63, r = tid >> 6;
#pragma unroll
    for (int i = 0; i < 16; ++i) {
        const int p = r + 4 * i;
        const float v = sw[0 * 64 + p] * x2P[((size_t)b * 512 + sj[0 * 64 + p]) * 512 + cb + c]
                      + sw[1 * 64 + p] * x2P[((size_t)b * 512 + sj[1 * 64 + p]) * 512 + cb + c]
                      + sw[2 * 64 + p] * x2P[((size_t)b * 512 + sj[2 * 64 + p]) * 512 + cb + c];
        featP[((size_t)b * 2048 + nb + p) * 768 + 256 + cb + c] = v;
    }
}

// ---------------------------------------------------------------------------
// K1: stage-1 KNN + x2 transpose (everything interp1 needs). Small & fast.
//   [  0, 256)  knn1: xyz1 vs xyz2 -> idx1/w1   (32 queries/block)
//   [256, 512)  t_x2: x2 -> x2P (point-major)
// ---------------------------------------------------------------------------
__global__ __launch_bounds__(256) void k1_stage(const float* __restrict__ xyz1,
                                                const float* __restrict__ xyz2,
                                                const float* __restrict__ x2,
                                                float* __restrict__ x2P,
                                                int* __restrict__ idx1,
                                                float* __restrict__ w1) {
    __shared__ float4 smem4[1040];   // 16,640 B union: knn1 14,336 / transpose 16,640
    const int id = blockIdx.x;
    if (id < 256) {
        const int b  = id >> 6;
        const int nb = (id & 63) * 32;
        knn_tile<512>(xyz1, xyz2, 2048, b, nb, idx1, w1, smem4);
    } else {
        const int r  = id - 256;
        const int b  = r >> 6;
        const int nb = (r & 7) * 64;
        const int cb = ((r >> 3) & 7) * 64;
        transpose_tile(x2, x2P, 512, 512, 512, 0, b, nb, cb, smem4);
    }
}

// ---------------------------------------------------------------------------
// K2: compute-bound knn2 overlapped with all remaining memory-bound work
// (mutually independent). knn2 blocks dispatched first (longest pole).
//   [   0,1024)  knn2: xyz0 vs xyz1 -> idx2/w2   (32 queries/block, 1024 blk)
//   [1024,2048)  interp1: featP cols 256..767    (needs K1's idx1/w1 + x2P)
//   [2048,2560)  t_x1: x1 -> featP cols 0..255
//   [2560,2816)  copy x0 -> out channels 0..127
// ---------------------------------------------------------------------------
__global__ __launch_bounds__(256) void k2_stage(const float* __restrict__ xyz0,
                                                const float* __restrict__ xyz1,
                                                const float* __restrict__ x0,
                                                const float* __restrict__ x1,
                                                const float* __restrict__ x2P,
                                                const int* __restrict__ idx1,
                                                const float* __restrict__ w1,
                                                float* __restrict__ featP,
                                                int* __restrict__ idx2,
                                                float* __restrict__ w2,
                                                float* __restrict__ out) {
    __shared__ float4 smem4[2432];   // 38,912 B union: knn2 38,912 / transpose 16,640
    const int id = blockIdx.x;
    if (id < 1024) {
        const int b  = id >> 8;
        const int nb = (id & 255) * 32;
        knn_tile<2048>(xyz0, xyz1, 8192, b, nb, idx2, w2, smem4);
    } else if (id < 2048) {
        const int r  = id - 1024;
        const int b  = r >> 8;
        const int nb = (r & 31) * 64;
        const int cb = ((r >> 5) & 7) * 64;
        interp1_tile(x2P, idx1, w1, featP, b, nb, cb, smem4);
    } else if (id < 2560) {
        const int r  = id - 2048;
        const int b  = r >> 7;
        const int nb = (r & 31) * 64;
        const int cb = ((r >> 5) & 3) * 64;
        transpose_tile(x1, featP, 256, 2048, 768, 0, b, nb, cb, smem4);
    } else {
        const int r  = id - 2560;          // 0..255
        const int b  = r >> 6;
        const int lb = r & 63;
        const float4* src = (const float4*)x0;
        float4* dst = (float4*)out;
#pragma unroll
        for (int t = 0; t < 16; ++t) {
            const int i = lb * 4096 + t * 256 + threadIdx.x;   // 0..262143
            dst[(size_t)b * (896 * 2048) + i] = src[(size_t)b * (128 * 2048) + i];
        }
    }
}

// ---------------------------------------------------------------------------
// K3: final interp (unchanged): out[b][128+c][n] = sum_k w_k * featP[b][j_k][c].
// XCD swizzle: all 12 c-tiles of an n-tile on the same XCD (gather-row reuse).
// ---------------------------------------------------------------------------
__global__ __launch_bounds__(256) void final_interp(const float* __restrict__ featP,
                                                    const int* __restrict__ idx,
                                                    const float* __restrict__ w,
                                                    float* __restrict__ out) {
    __shared__ float tile[64][65];
    __shared__ int   sj[3][64];
    __shared__ float sw[3][64];
    const int b = blockIdx.y;
    const int id = blockIdx.x;
    const int ntile = (id & 7) * 16 + ((id >> 3) & 15);
    const int ctile = id >> 7;
    const int nb = ntile * 64;
    const int cb = ctile * 64;
    const int tid = threadIdx.x;

    if (tid < 64) {
#pragma unroll
        for (int k = 0; k < 3; ++k) {
            sj[k][tid] = idx[(b * 3 + k) * 8192 + nb + tid];
            sw[k][tid] = w[(b * 3 + k) * 8192 + nb + tid];
        }
    }
    __syncthreads();

    {
        const int c = tid & 63, r = tid >> 6;
#pragma unroll
        for (int i = 0; i < 16; ++i) {
            const int p = r + 4 * i;
            const float v = sw[0][p] * featP[((size_t)b * 2048 + sj[0][p]) * 768 + cb + c]
                          + sw[1][p] * featP[((size_t)b * 2048 + sj[1][p]) * 768 + cb + c]
                          + sw[2][p] * featP[((size_t)b * 2048 + sj[2][p]) * 768 + cb + c];
            tile[p][c] = v;
        }
    }
    __syncthreads();
    {
        const int p = tid & 63, r = tid >> 6;
#pragma unroll
        for (int i = 0; i < 16; ++i) {
            const int cl = r + 4 * i;
            out[((size_t)b * 896 + 128 + cb + cl) * 8192 + nb + p] = tile[p][cl];
        }
    }
}

extern "C" void kernel_launch(void* const* d_in, const int* in_sizes, int n_in,
                              void* d_out, int out_size, void* d_ws, size_t ws_size,
                              hipStream_t stream) {
    const float* xyz0 = (const float*)d_in[0];  // [4,8192,3]
    const float* xyz1 = (const float*)d_in[1];  // [4,2048,3]
    const float* xyz2 = (const float*)d_in[2];  // [4,512,3]
    const float* x0   = (const float*)d_in[3];  // [4,128,8192]
    const float* x1   = (const float*)d_in[4];  // [4,256,2048]
    const float* x2   = (const float*)d_in[5];  // [4,512,512]
    float* out = (float*)d_out;                 // [4,896,8192]

    // Workspace layout (bytes), no aliasing (total 30,343,168):
    //   featP : float[4*2048*768]  @ 0          (25,165,824)
    //   idx1  : int  [4*3*2048]    @ 25,165,824 (98,304)
    //   w1    : float[4*3*2048]    @ 25,264,128 (98,304)
    //   idx2  : int  [4*3*8192]    @ 25,362,432 (393,216)
    //   w2    : float[4*3*8192]    @ 25,755,648 (393,216)
    //   x2P   : float[4*512*512]   @ 26,148,864 (4,194,304)
    char* ws = (char*)d_ws;
    float* featP = (float*)(ws + 0);
    int*   idx1  = (int*)(ws + 25165824);
    float* w1    = (float*)(ws + 25264128);
    int*   idx2  = (int*)(ws + 25362432);
    float* w2    = (float*)(ws + 25755648);
    float* x2P   = (float*)(ws + 26148864);

    // K1: stage-1 KNN + x2 transpose (small).
    k1_stage<<<dim3(512), 256, 0, stream>>>(xyz1, xyz2, x2, x2P, idx1, w1);
    // K2: knn2 (compute) overlapped with interp1 + t_x1 + copy_x0 (memory).
    k2_stage<<<dim3(2816), 256, 0, stream>>>(xyz0, xyz1, x0, x1, x2P, idx1, w1,
                                             featP, idx2, w2, out);
    // K3: final interpolation into out channels 128..895.
    final_interp<<<dim3(1536, 4), 256, 0, stream>>>(featP, idx2, w2, out);
}

// Round 3
// 213.861 us; speedup vs baseline: 1.6463x; 1.0197x over previous
//
#include <hip/hip_runtime.h>

#define BIG 3.0e38f

// ---------------------------------------------------------------------------
// Branchless top-3 insert (strict < keeps lowest index on ties, matching
// top_k). Straight-line: 3 v_cmp + 10 v_cndmask, keeps the scan loop a single
// basic block so the compiler can unroll + pipeline the LDS reads.
// ---------------------------------------------------------------------------
__device__ __forceinline__ void insert3(float d, int s,
                                        float& d0, float& d1, float& d2,
                                        int& i0, int& i1, int& i2) {
    const bool b0 = d < d0;
    const bool b1 = d < d1;
    const bool b2 = d < d2;
    d2 = b1 ? d1 : (b2 ? d : d2);   // reads old d1/i1
    i2 = b1 ? i1 : (b2 ? s : i2);
    d1 = b0 ? d0 : (b1 ? d : d1);   // reads old d0/i0
    i1 = b0 ? i0 : (b1 ? s : i1);
    d0 = b0 ? d : d0;
    i0 = b0 ? s : i0;
}

// ---------------------------------------------------------------------------
// Single-pass KNN tile: 256 threads = 32 queries x 8 candidate-splits.
// All S candidates staged once in LDS (float4: x,y,z,|p|^2). Each thread
// scans S/8 candidates; 8 split top-3 lists merged in LDS in ascending split
// order (tie order == full ascending scan). Writes idx/w directly.
// ---------------------------------------------------------------------------
template <int S>
__device__ void knn_tile(const float* __restrict__ xyzF, const float* __restrict__ xyzC,
                         int N, int b, int nb,
                         int* __restrict__ idx, float* __restrict__ w,
                         void* smem) {
    constexpr int SPC = S / 8;
    float4* sc  = (float4*)smem;                       // S * 16 B
    float*  smd = (float*)((char*)smem + S * 16);      // [256][3] floats
    int*    smi = (int*)((char*)smem + S * 16 + 3072); // [256][3] ints
    const int tid = threadIdx.x;

    for (int i = tid; i < S; i += 256) {
        const float x = xyzC[(b * S + i) * 3 + 0];
        const float y = xyzC[(b * S + i) * 3 + 1];
        const float z = xyzC[(b * S + i) * 3 + 2];
        sc[i] = make_float4(x, y, z, x * x + y * y + z * z);
    }
    __syncthreads();

    const int q  = tid & 31;          // query within tile
    const int sp = tid >> 5;          // candidate split 0..7
    const int n  = nb + q;
    const float ax = xyzF[(b * N + n) * 3 + 0];
    const float ay = xyzF[(b * N + n) * 3 + 1];
    const float az = xyzF[(b * N + n) * 3 + 2];
    const float an = ax * ax + ay * ay + az * az;

    float d0 = BIG, d1 = BIG, d2 = BIG;
    int i0 = 0, i1 = 0, i2 = 0;
    const int s0 = sp * SPC;
#pragma unroll 8
    for (int s = s0; s < s0 + SPC; ++s) {
        const float4 p = sc[s];       // 2 distinct addrs per wave -> ~free
        const float t = ax * p.x + ay * p.y + az * p.z;
        const float d = an + p.w - 2.0f * t;   // matches ref formula exactly
        insert3(d, s, d0, d1, d2, i0, i1, i2);
    }

    smd[tid * 3 + 0] = d0; smi[tid * 3 + 0] = i0;   // stride 3 -> <=2-way, free
    smd[tid * 3 + 1] = d1; smi[tid * 3 + 1] = i1;
    smd[tid * 3 + 2] = d2; smi[tid * 3 + 2] = i2;
    __syncthreads();

    if (tid < 32) {                   // one thread per query merges 8 splits
        float e0 = BIG, e1 = BIG, e2 = BIG;
        int j0 = 0, j1 = 0, j2 = 0;
#pragma unroll
        for (int ch = 0; ch < 8; ++ch) {
#pragma unroll
            for (int k = 0; k < 3; ++k) {
                insert3(smd[(ch * 32 + tid) * 3 + k], smi[(ch * 32 + tid) * 3 + k],
                        e0, e1, e2, j0, j1, j2);
            }
        }
        const float r0 = 1.0f / (e0 + 1e-8f);
        const float r1 = 1.0f / (e1 + 1e-8f);
        const float r2 = 1.0f / (e2 + 1e-8f);
        const float rs = r0 + r1 + r2;
        const int nn = nb + tid;
        idx[(b * 3 + 0) * N + nn] = j0;
        idx[(b * 3 + 1) * N + nn] = j1;
        idx[(b * 3 + 2) * N + nn] = j2;
        w[(b * 3 + 0) * N + nn] = r0 / rs;
        w[(b * 3 + 1) * N + nn] = r1 / rs;
        w[(b * 3 + 2) * N + nn] = r2 / rs;
    }
}

// ---------------------------------------------------------------------------
// 64x64 tile transpose [B,C,N] -> point-major out[b][n][c] (row stride OS).
// ---------------------------------------------------------------------------
__device__ void transpose_tile(const float* __restrict__ in, float* __restrict__ out,
                               int C, int N, int OS,
                               int b, int nb, int cb, void* smem) {
    float (*s)[65] = (float (*)[65])smem;
    const int lo = threadIdx.x & 63;
    const int r  = threadIdx.x >> 6;
#pragma unroll
    for (int i = 0; i < 16; ++i) {
        const int cl = r + 4 * i;
        s[cl][lo] = in[((size_t)b * C + cb + cl) * N + nb + lo];
    }
    __syncthreads();
#pragma unroll
    for (int i = 0; i < 16; ++i) {
        const int pl = r + 4 * i;
        out[((size_t)b * N + nb + pl) * OS + cb + lo] = s[lo][pl];
    }
}

// ---------------------------------------------------------------------------
// K1: ALL mutually-independent prep work in one dispatch, knn2 first (pole).
//   [   0,1024)  knn2: xyz0 vs xyz1 -> idx2/w2   (32 q/blk, 1024 blocks)
//   [1024,1280)  knn1: xyz1 vs xyz2 -> idx1/w1   (32 q/blk, 256 blocks)
//   [1280,1536)  t_x2: x2 -> x2P [B][512][512]
//   [1536,2048)  t_x1: x1 -> x1P [B][2048][256]
//   [2048,2304)  copy x0 -> out channels 0..127
// ---------------------------------------------------------------------------
__global__ __launch_bounds__(256) void k1_stage(const float* __restrict__ xyz0,
                                                const float* __restrict__ xyz1,
                                                const float* __restrict__ xyz2,
                                                const float* __restrict__ x0,
                                                const float* __restrict__ x1,
                                                const float* __restrict__ x2,
                                                float* __restrict__ x1P,
                                                float* __restrict__ x2P,
                                                int* __restrict__ idx1,
                                                float* __restrict__ w1,
                                                int* __restrict__ idx2,
                                                float* __restrict__ w2,
                                                float* __restrict__ out) {
    __shared__ float4 smem4[2432];   // 38,912 B union: knn2 38,912 / transpose 16,640
    const int id = blockIdx.x;
    if (id < 1024) {
        const int b  = id >> 8;
        const int nb = (id & 255) * 32;
        knn_tile<2048>(xyz0, xyz1, 8192, b, nb, idx2, w2, smem4);
    } else if (id < 1280) {
        const int r  = id - 1024;
        const int b  = r >> 6;
        const int nb = (r & 63) * 32;
        knn_tile<512>(xyz1, xyz2, 2048, b, nb, idx1, w1, smem4);
    } else if (id < 1536) {
        const int r  = id - 1280;
        const int b  = r >> 6;
        const int nb = (r & 7) * 64;
        const int cb = ((r >> 3) & 7) * 64;
        transpose_tile(x2, x2P, 512, 512, 512, b, nb, cb, smem4);
    } else if (id < 2048) {
        const int r  = id - 1536;
        const int b  = r >> 7;
        const int nb = (r & 31) * 64;
        const int cb = ((r >> 5) & 3) * 64;
        transpose_tile(x1, x1P, 256, 2048, 256, b, nb, cb, smem4);
    } else {
        const int r  = id - 2048;          // 0..255
        const int b  = r >> 6;
        const int lb = r & 63;
        const float4* src = (const float4*)x0;
        float4* dst = (float4*)out;
#pragma unroll
        for (int t = 0; t < 16; ++t) {
            const int i = lb * 4096 + t * 256 + threadIdx.x;   // 0..262143
            dst[(size_t)b * (896 * 2048) + i] = src[(size_t)b * (128 * 2048) + i];
        }
    }
}

// ---------------------------------------------------------------------------
// K2: final output via composed interpolation. Per batch, 12 c-tiles x 128
// n-tiles (64x64 tiles). c-tiles 0..3: out[128+cb+c][n] = 3-gather of x1P
// (w2). c-tiles 4..11: out[384+cb'+c][n] = 9-gather of x2P with composed
// weights w2_k*w1_m[j_k] (stage-1 interp algebraically folded in; x2P is
// 1 MB/batch -> per-XCD L2-resident). XCD swizzle: all c-tiles of an n-tile
// on the same XCD (gather-row reuse).
// ---------------------------------------------------------------------------
__global__ __launch_bounds__(256) void final_fused(const float* __restrict__ x1P,
                                                   const float* __restrict__ x2P,
                                                   const int* __restrict__ idx1,
                                                   const float* __restrict__ w1,
                                                   const int* __restrict__ idx2,
                                                   const float* __restrict__ w2,
                                                   float* __restrict__ out) {
    __shared__ float tile[64][65];
    __shared__ int   sj[9][64];
    __shared__ float sw[9][64];
    const int b = blockIdx.y;
    const int id = blockIdx.x;
    const int ntile = (id & 7) * 16 + ((id >> 3) & 15);   // 0..127
    const int ctile = id >> 7;                            // 0..11
    const int nb = ntile * 64;
    const int tid = threadIdx.x;

    if (ctile < 4) {
        // ------- channels 128..383: 3-gather of x1P with w2 -------
        if (tid < 64) {
#pragma unroll
            for (int k = 0; k < 3; ++k) {
                sj[k][tid] = idx2[(b * 3 + k) * 8192 + nb + tid];
                sw[k][tid] = w2[(b * 3 + k) * 8192 + nb + tid];
            }
        }
        __syncthreads();
        const int cb = ctile * 64;
        {
            const int c = tid & 63, r = tid >> 6;
            const float* xb = x1P + (size_t)b * 2048 * 256 + cb + c;
#pragma unroll
            for (int i = 0; i < 16; ++i) {
                const int p = r + 4 * i;
                const float v = sw[0][p] * xb[(size_t)sj[0][p] * 256]
                              + sw[1][p] * xb[(size_t)sj[1][p] * 256]
                              + sw[2][p] * xb[(size_t)sj[2][p] * 256];
                tile[p][c] = v;
            }
        }
        __syncthreads();
        {
            const int p = tid & 63, r = tid >> 6;
#pragma unroll
            for (int i = 0; i < 16; ++i) {
                const int cl = r + 4 * i;
                out[((size_t)b * 896 + 128 + cb + cl) * 8192 + nb + p] = tile[p][cl];
            }
        }
    } else {
        // ------- channels 384..895: 9-gather of x2P, composed weights -------
        if (tid < 64) {
            const int n = nb + tid;
#pragma unroll
            for (int k = 0; k < 3; ++k) {
                const int   j  = idx2[(b * 3 + k) * 8192 + n];
                const float wk = w2[(b * 3 + k) * 8192 + n];
#pragma unroll
                for (int m = 0; m < 3; ++m) {
                    sj[k * 3 + m][tid] = idx1[(b * 3 + m) * 2048 + j];
                    sw[k * 3 + m][tid] = wk * w1[(b * 3 + m) * 2048 + j];
                }
            }
        }
        __syncthreads();
        const int cb = (ctile - 4) * 64;   // 0..448 within x2 channel block
        {
            const int c = tid & 63, r = tid >> 6;
            const float* xb = x2P + (size_t)b * 512 * 512 + cb + c;
#pragma unroll
            for (int i = 0; i < 16; ++i) {
                const int p = r + 4 * i;
                float v = 0.0f;
#pragma unroll
                for (int j = 0; j < 9; ++j) {
                    v += sw[j][p] * xb[(size_t)sj[j][p] * 512];
                }
                tile[p][c] = v;
            }
        }
        __syncthreads();
        {
            const int p = tid & 63, r = tid >> 6;
#pragma unroll
            for (int i = 0; i < 16; ++i) {
                const int cl = r + 4 * i;
                out[((size_t)b * 896 + 384 + cb + cl) * 8192 + nb + p] = tile[p][cl];
            }
        }
    }
}

extern "C" void kernel_launch(void* const* d_in, const int* in_sizes, int n_in,
                              void* d_out, int out_size, void* d_ws, size_t ws_size,
                              hipStream_t stream) {
    const float* xyz0 = (const float*)d_in[0];  // [4,8192,3]
    const float* xyz1 = (const float*)d_in[1];  // [4,2048,3]
    const float* xyz2 = (const float*)d_in[2];  // [4,512,3]
    const float* x0   = (const float*)d_in[3];  // [4,128,8192]
    const float* x1   = (const float*)d_in[4];  // [4,256,2048]
    const float* x2   = (const float*)d_in[5];  // [4,512,512]
    float* out = (float*)d_out;                 // [4,896,8192]

    // Workspace layout (bytes), total 13,565,952 (featP eliminated):
    //   x1P   : float[4*2048*256] @ 0          (8,388,608)  point-major x1
    //   x2P   : float[4*512*512]  @ 8,388,608  (4,194,304)  point-major x2
    //   idx1  : int  [4*3*2048]   @ 12,582,912 (98,304)
    //   w1    : float[4*3*2048]   @ 12,681,216 (98,304)
    //   idx2  : int  [4*3*8192]   @ 12,779,520 (393,216)
    //   w2    : float[4*3*8192]   @ 13,172,736 (393,216)
    char* ws = (char*)d_ws;
    float* x1P  = (float*)(ws + 0);
    float* x2P  = (float*)(ws + 8388608);
    int*   idx1 = (int*)(ws + 12582912);
    float* w1   = (float*)(ws + 12681216);
    int*   idx2 = (int*)(ws + 12779520);
    float* w2   = (float*)(ws + 13172736);

    // K1: both KNNs + both point-major transposes + x0 copy (all independent).
    k1_stage<<<dim3(2304), 256, 0, stream>>>(xyz0, xyz1, xyz2, x0, x1, x2,
                                             x1P, x2P, idx1, w1, idx2, w2, out);
    // K2: composed final interpolation (stage-1 folded in algebraically).
    final_fused<<<dim3(1536, 4), 256, 0, stream>>>(x1P, x2P, idx1, w1, idx2, w2, out);
}